// Round 12
// baseline (1241.370 us; speedup 1.0000x reference)
//
#include <hip/hip_runtime.h>

typedef __attribute__((ext_vector_type(8))) short bf16x8;
typedef __attribute__((ext_vector_type(4))) float f32x4;

#define L_DIM 24
#define B_DIM 32
#define S_DIM 512
#define H_DIM 1024
#define M_DIM 16384      // B*S
#define K_DIM 24576      // L*H
#define N_REAL 900
#define NP 1024          // padded N

// round-to-nearest-even fp32 -> bf16
__device__ __forceinline__ short f2bf(float f) {
  unsigned u = __builtin_bit_cast(unsigned, f);
  u += 0x7FFFu + ((u >> 16) & 1u);
  return (short)(u >> 16);
}

// ---- C1: per-batch flags + local prefix of unique nonzero starts (sorted input)
__global__ __launch_bounds__(512)
void compact1_kernel(const int* __restrict__ starts, int* __restrict__ upos,
                     int* __restrict__ counts) {
  __shared__ int sc[512];
  const int b = blockIdx.x, t = threadIdx.x;
  const int v = starts[b * 512 + t];
  const int prev = (t > 0) ? starts[b * 512 + t - 1] : -1;
  const int flag = (v != 0 && v != prev) ? 1 : 0;
  sc[t] = flag;
  __syncthreads();
#pragma unroll
  for (int off = 1; off < 512; off <<= 1) {
    const int x = (t >= off) ? sc[t - off] : 0;
    __syncthreads();
    sc[t] += x;
    __syncthreads();
  }
  upos[b * 512 + t] = flag ? (sc[t] - 1) : -1;
  if (t == 511) counts[b] = sc[511];
}

// ---- C2: scan counts -> offsets, Mc, Mc_pad (256-mult); pad idx tail with row 0
__global__ __launch_bounds__(256)
void compact2_kernel(const int* __restrict__ counts, int* __restrict__ offs,
                     int* __restrict__ meta, int* __restrict__ idx) {
  __shared__ int s0, s1;
  if (threadIdx.x == 0) {
    int acc = 0;
    for (int b = 0; b < 32; ++b) { offs[b] = acc; acc += counts[b]; }
    meta[0] = acc;                        // Mc
    meta[1] = (acc + 255) & ~255;         // Mc_pad (BM=256 multiple)
    s0 = acc; s1 = (acc + 255) & ~255;
  }
  __syncthreads();
  for (int j = s0 + threadIdx.x; j < s1; j += 256) idx[j] = 0;  // pad -> row 0
}

// ---- C3: scatter compact indices: idx[off_b + pos] = b*512 + value
__global__ __launch_bounds__(512)
void compact3_kernel(const int* __restrict__ starts, const int* __restrict__ upos,
                     const int* __restrict__ offs, int* __restrict__ idx) {
  const int b = blockIdx.x, t = threadIdx.x;
  const int p = upos[b * 512 + t];
  if (p >= 0) idx[offs[b] + p] = b * 512 + starts[b * 512 + t];
}

// ---- P0: compacted A: row j <- hs row idx[j], fp32->bf16, pre-swizzled by j&7:
// element (j,k) at k' = (k & ~63) + (((k>>3 & 7) ^ (j & 7)) * 8) + (k & 7)
__global__ __launch_bounds__(256)
void conv_a_kernel(const float* __restrict__ hs, const int* __restrict__ idx,
                   const int* __restrict__ meta, unsigned short* __restrict__ a) {
  const int mcp = meta[1];
  for (int j = blockIdx.x; j < mcp; j += gridDim.x) {
    const int m = idx[j];
    const int b = m >> 9, s = m & 511;
    const int j7 = j & 7;
    unsigned short* dstRow = a + (size_t)j * K_DIM;
#pragma unroll
    for (int i = 0; i < 12; ++i) {
      const int g = threadIdx.x + i * 256;        // granule (8 elems)
      const int l = g >> 7;
      const int h = (g & 127) * 8;
      const float* src = hs + (((size_t)l * B_DIM + b) * S_DIM + s) * H_DIM + h;
      float4 f0 = *(const float4*)src;
      float4 f1 = *(const float4*)(src + 4);
      bf16x8 p;
      p[0] = f2bf(f0.x); p[1] = f2bf(f0.y); p[2] = f2bf(f0.z); p[3] = f2bf(f0.w);
      p[4] = f2bf(f1.x); p[5] = f2bf(f1.y); p[6] = f2bf(f1.z); p[7] = f2bf(f1.w);
      const int slot = (g & 7) ^ j7;
      *(bf16x8*)(dstRow + (g & ~7) * 8 + slot * 8) = p;
    }
  }
}

// ---- P1: W1 [K][900] -> W1T bf16 [1024][K], zero-padded rows, swizzled (by n&7)
__global__ __launch_bounds__(256)
void prep_w1t_kernel(const float* __restrict__ w1, unsigned short* __restrict__ w1t) {
  __shared__ unsigned short t[64][72];
  const int n0 = blockIdx.x * 64;
  const int k0 = blockIdx.y * 64;
  const int tid = threadIdx.x;
  {
    const int nl = tid & 63;
    const int n = n0 + nl;
#pragma unroll
    for (int p = 0; p < 16; ++p) {
      const int kl = p * 4 + (tid >> 6);
      float v = (n < N_REAL) ? w1[(size_t)(k0 + kl) * N_REAL + n] : 0.f;
      t[nl][kl] = (unsigned short)f2bf(v);
    }
  }
  __syncthreads();
  {
    const int kl = tid & 63;
#pragma unroll
    for (int p = 0; p < 16; ++p) {
      const int nl2 = p * 4 + (tid >> 6);
      const int n = n0 + nl2;
      const int slot = ((kl >> 3) ^ (n & 7)) & 7;
      w1t[(size_t)n * K_DIM + k0 + slot * 8 + (kl & 7)] = t[nl2][kl];
    }
  }
}

// ---- P2: W2T fp32 [40][1024] (transposed, padded) + b1 padded [1024]
__global__ __launch_bounds__(256)
void prep_small_kernel(const float* __restrict__ w2, const float* __restrict__ b1,
                       float* __restrict__ w2t, float* __restrict__ b1p) {
  const int i = blockIdx.x * 256 + threadIdx.x;
  if (i < 40 * NP) {
    const int j = i >> 10, k = i & (NP - 1);
    w2t[i] = (k < N_REAL) ? w2[(size_t)k * 40 + j] : 0.f;
  }
  const int t2 = i - 40 * NP;
  if (t2 >= 0 && t2 < NP)
    b1p[t2] = (t2 < N_REAL) ? b1[t2] : 0.f;
}

// =====================================================================
// G1 (split-K x3): partial[kh] = A @ W1T^T over K-range [kh*8192, +8192).
// 256x256 tile, BK=64, 4-phase m201 cadence (R11-verified). 492 active
// blocks (41 panels x 4 n x 3 kh) -> ~2 full rounds over 256 CUs vs
// R11's 164 blocks / 1 round at 64% fill. Epilogue writes RAW partials;
// bias+relu+sum move to layer23.
// =====================================================================
#define SBAR() do { __builtin_amdgcn_sched_barrier(0); __builtin_amdgcn_s_barrier(); __builtin_amdgcn_sched_barrier(0); } while (0)
#define WAIT_LGKM0() do { asm volatile("s_waitcnt lgkmcnt(0)" ::: "memory"); __builtin_amdgcn_sched_barrier(0); } while (0)
#define VMWAIT(N) do { asm volatile("s_waitcnt vmcnt(" #N ")" ::: "memory"); __builtin_amdgcn_sched_barrier(0); } while (0)

// stage one 128-row half-tile (16 KiB): 2 x global_load_lds per thread
#define STAGE(DSTREG, GBASE, ROWBASE, HALF, TK) do {                                   \
  _Pragma("unroll")                                                                    \
  for (int _i = 0; _i < 2; ++_i) {                                                     \
    const int _ch = wid * 2 + _i;                                                      \
    const int _row = (HALF) * 128 + _ch * 8 + (lane >> 3);                             \
    __builtin_amdgcn_global_load_lds(                                                  \
      (const __attribute__((address_space(1))) void*)((GBASE) +                        \
          (size_t)((ROWBASE) + _row) * K_DIM + (TK) * 64 + (lane & 7) * 8),            \
      (__attribute__((address_space(3))) void*)((DSTREG) + (HALF) * 16384 + _ch * 1024), \
      16, 0, 0);                                                                       \
  }                                                                                    \
} while (0)

// A fragment rows: half = MIBASE>>2 (0 or 1) -> rows half*128 + wr*64 + mi*16
#define LDA4(AV, MIBASE, ABUF) do {                                                    \
  _Pragma("unroll")                                                                    \
  for (int _mi = 0; _mi < 4; ++_mi) {                                                  \
    _Pragma("unroll")                                                                  \
    for (int _kk = 0; _kk < 2; ++_kk) {                                                \
      const int _r = ((MIBASE) >> 2) * 128 + wr * 64 + _mi * 16 + r15;                 \
      AV[_mi][_kk] = *(const bf16x8*)((ABUF) + _r * 128 + (((_kk)*4 + hi4) ^ (_r & 7)) * 16); \
    }                                                                                  \
  }                                                                                    \
} while (0)

// B fragment rows: half = NIBASE>>1 (0 or 1) -> rows half*128 + wc*32 + ni*16
#define LDB2(BV, NIBASE, BBUF) do {                                                    \
  _Pragma("unroll")                                                                    \
  for (int _ni = 0; _ni < 2; ++_ni) {                                                  \
    _Pragma("unroll")                                                                  \
    for (int _kk = 0; _kk < 2; ++_kk) {                                                \
      const int _r = ((NIBASE) >> 1) * 128 + wc * 32 + _ni * 16 + r15;                 \
      BV[_ni][_kk] = *(const bf16x8*)((BBUF) + _r * 128 + (((_kk)*4 + hi4) ^ (_r & 7)) * 16); \
    }                                                                                  \
  }                                                                                    \
} while (0)

#define MFMA_Q(AV, BV, MIBASE, NIBASE) do {                                            \
  _Pragma("unroll")                                                                    \
  for (int _mi = 0; _mi < 4; ++_mi)                                                    \
    _Pragma("unroll")                                                                  \
    for (int _ni = 0; _ni < 2; ++_ni)                                                  \
      _Pragma("unroll")                                                                \
      for (int _kk = 0; _kk < 2; ++_kk)                                                \
        acc[(MIBASE) + _mi][(NIBASE) + _ni] = __builtin_amdgcn_mfma_f32_16x16x32_bf16( \
            AV[_mi][_kk], BV[_ni][_kk], acc[(MIBASE) + _mi][(NIBASE) + _ni], 0, 0, 0); \
} while (0)

// one K-tile = 4 phases, quadrants (Aa,Ba)(Aa,Bb)(Ab,Bb)(Ab,Ba).
// S1: stage A_b(t+1) into ABN; S2: B_b(t+1) into BBN;
// S3: B_a(t+2) into BB; S4: A_a(t+2) into AB.
#define TILE_BODY(T, AB, BB, ABN, BBN, S1, S2, S3, S4, W1STMT, W4STMT) do {            \
  /* ---- phase 1 ---- */                                                              \
  LDA4(av, 0, (AB));                                                                   \
  LDB2(bv0, 0, (BB));                                                                  \
  if (S1) STAGE((ABN), a, m0, 1, (T) + 1);                                             \
  SBAR();                                                                              \
  WAIT_LGKM0();                                                                        \
  __builtin_amdgcn_s_setprio(1);                                                       \
  MFMA_Q(av, bv0, 0, 0);                                                               \
  __builtin_amdgcn_s_setprio(0);                                                       \
  W1STMT;                                                                              \
  SBAR();                                                                              \
  /* ---- phase 2 ---- */                                                              \
  LDB2(bv1, 2, (BB));                                                                  \
  if (S2) STAGE((BBN), w1t, n0, 1, (T) + 1);                                           \
  SBAR();                                                                              \
  WAIT_LGKM0();                                                                        \
  __builtin_amdgcn_s_setprio(1);                                                       \
  MFMA_Q(av, bv1, 0, 2);                                                               \
  __builtin_amdgcn_s_setprio(0);                                                       \
  SBAR();                                                                              \
  /* ---- phase 3 ---- */                                                              \
  LDA4(av, 4, (AB));                                                                   \
  if (S3) STAGE((BB), w1t, n0, 0, (T) + 2);                                            \
  SBAR();                                                                              \
  WAIT_LGKM0();                                                                        \
  __builtin_amdgcn_s_setprio(1);                                                       \
  MFMA_Q(av, bv1, 4, 2);                                                               \
  __builtin_amdgcn_s_setprio(0);                                                       \
  SBAR();                                                                              \
  /* ---- phase 4 ---- */                                                              \
  if (S4) STAGE((AB), a, m0, 0, (T) + 2);                                              \
  SBAR();                                                                              \
  WAIT_LGKM0();                                                                        \
  __builtin_amdgcn_s_setprio(1);                                                       \
  MFMA_Q(av, bv0, 4, 0);                                                               \
  __builtin_amdgcn_s_setprio(0);                                                       \
  W4STMT;                                                                              \
  SBAR();                                                                              \
} while (0)

__global__ __launch_bounds__(512, 2)
void gemm1_8ph_kernel(const unsigned short* __restrict__ a,
                      const unsigned short* __restrict__ w1t,
                      const int* __restrict__ meta,
                      float* __restrict__ h1p) {
  const int mcp = meta[1];
  const int n_panels = mcp >> 8;

  // identity work decode: actives are the contiguous prefix hw < 12*n_panels,
  // so dispatch round-robin spreads them evenly over XCDs (41/XCD +- 1).
  const int hw = blockIdx.x;
  const int mb = hw / 12;
  if (mb >= n_panels) return;
  const int rem = hw - mb * 12;
  const int nb = rem & 3;
  const int kh = rem >> 2;            // 0..2 : K third
  const int m0 = mb * 256;
  const int n0 = nb * 256;
  const int t0 = kh * 128;            // 128 K-tiles per third

  extern __shared__ char L[];   // 128 KiB: A0|B0|A1|B1, 32 KiB each
  char* const Ab0 = L;
  char* const Bb0 = L + 32768;
  char* const Ab1 = L + 65536;
  char* const Bb1 = L + 65536 + 32768;

  const int tid = threadIdx.x;
  const int lane = tid & 63;
  const int wid = tid >> 6;          // 0..7
  const int wr = wid >> 2;           // 0..1 (64-row band within each 128-half)
  const int wc = wid & 3;            // 0..3 (32-col band within each 128-half)
  const int r15 = lane & 15;
  const int hi4 = lane >> 4;         // 0..3

  f32x4 acc[8][4] = {};
  bf16x8 av[4][2], bv0[2][2], bv1[2][2];

  // prologue in steady queue order: [Ba(t0), Aa(t0), Ab(t0), Bb(t0), Ba(t0+1), Aa(t0+1)]
  STAGE(Bb0, w1t, n0, 0, t0);
  STAGE(Ab0, a, m0, 0, t0);
  STAGE(Ab0, a, m0, 1, t0);
  STAGE(Bb0, w1t, n0, 1, t0);
  STAGE(Bb1, w1t, n0, 0, t0 + 1);
  STAGE(Ab1, a, m0, 0, t0 + 1);
  VMWAIT(8);     // land Ba(t0), Aa(t0); keep 4 halves in flight (steady state)
  SBAR();

  for (int kt = 0; kt < 63; ++kt) {
    const int t = t0 + 2 * kt;
    TILE_BODY(t,     Ab0, Bb0, Ab1, Bb1, 1, 1, 1, 1, VMWAIT(6), VMWAIT(8));
    TILE_BODY(t + 1, Ab1, Bb1, Ab0, Bb0, 1, 1, 1, 1, VMWAIT(6), VMWAIT(8));
  }
  // tail: t0+126 stages only A_b/B_b(t0+127); full drain. t0+127 computes.
  TILE_BODY(t0 + 126, Ab0, Bb0, Ab1, Bb1, 1, 1, 0, 0, VMWAIT(6), VMWAIT(0));
  TILE_BODY(t0 + 127, Ab1, Bb1, Ab0, Bb0, 0, 0, 0, 0, (void)0, (void)0);

  // epilogue: RAW partial sums; C/D: col = lane&15, row = (lane>>4)*4 + r
  float* dst = h1p + (size_t)kh * ((size_t)M_DIM * NP);
#pragma unroll
  for (int mi = 0; mi < 8; ++mi) {
#pragma unroll
    for (int ni = 0; ni < 4; ++ni) {
      const int n = n0 + (ni >> 1) * 128 + wc * 32 + (ni & 1) * 16 + r15;
#pragma unroll
      for (int rr = 0; rr < 4; ++rr) {
        const int m = m0 + (mi >> 2) * 128 + wr * 64 + (mi & 3) * 16 + hi4 * 4 + rr;
        dst[(size_t)m * NP + n] = acc[mi][ni][rr];
      }
    }
  }
}

// ---- K2: logits = sigmoid(relu(relu(p0+p1+p2+b1) @ W2 + b2) @ W3 + b3),
//          one wave per COMPACT row j; writes at original position idx[j].
__global__ __launch_bounds__(256)
void layer23_kernel(const float* __restrict__ h1p, const float* __restrict__ w2t,
                    const float* __restrict__ b1p, const float* __restrict__ b2,
                    const float* __restrict__ w3, const float* __restrict__ b3,
                    const int* __restrict__ idx, const int* __restrict__ meta,
                    float* __restrict__ logits) {
  const int j = (blockIdx.x * 256 + threadIdx.x) >> 6;
  if (j >= meta[0]) return;
  const int lane = threadIdx.x & 63;
  const float* p0 = h1p + (size_t)j * NP;
  const float* p1 = p0 + (size_t)M_DIM * NP;
  const float* p2 = p1 + (size_t)M_DIM * NP;
  float acc = 0.f;
  if (lane < 40) {
    const float* wrow = w2t + lane * NP;
    for (int k = 0; k < NP; k += 4) {
      float4 a0 = *(const float4*)(p0 + k);
      float4 a1 = *(const float4*)(p1 + k);
      float4 a2 = *(const float4*)(p2 + k);
      float4 bb = *(const float4*)(b1p + k);
      float4 w0 = *(const float4*)(wrow + k);
      float x0 = a0.x + a1.x + a2.x + bb.x; x0 = x0 > 0.f ? x0 : 0.f;
      float x1 = a0.y + a1.y + a2.y + bb.y; x1 = x1 > 0.f ? x1 : 0.f;
      float x2 = a0.z + a1.z + a2.z + bb.z; x2 = x2 > 0.f ? x2 : 0.f;
      float x3 = a0.w + a1.w + a2.w + bb.w; x3 = x3 > 0.f ? x3 : 0.f;
      acc += x0 * w0.x + x1 * w0.y + x2 * w0.z + x3 * w0.w;
    }
    acc += b2[lane];
    acc = acc > 0.f ? acc : 0.f;
    acc *= w3[lane];
  }
#pragma unroll
  for (int off = 32; off > 0; off >>= 1)
    acc += __shfl_down(acc, off);
  if (lane == 0)
    logits[idx[j]] = 1.f / (1.f + expf(-(acc + b3[0])));
}

// ---- K3: ragged gather
__global__ __launch_bounds__(256)
void gather_kernel(const int* __restrict__ starts, const float* __restrict__ logits,
                   float* __restrict__ out) {
  const int i = blockIdx.x * 256 + threadIdx.x;
  if (i >= M_DIM) return;
  const int st = starts[i];
  int idx = st;
  if (idx < 0) idx = 0;
  if (idx > S_DIM - 1) idx = S_DIM - 1;
  out[i] = (st != 0) ? logits[((i >> 9) << 9) + idx] : 0.f;
}

extern "C" void kernel_launch(void* const* d_in, const int* in_sizes, int n_in,
                              void* d_out, int out_size, void* d_ws, size_t ws_size,
                              hipStream_t stream) {
  const float* hs = (const float*)d_in[0];
  const float* W1 = (const float*)d_in[1];
  const float* b1 = (const float*)d_in[2];
  const float* W2 = (const float*)d_in[3];
  const float* b2 = (const float*)d_in[4];
  const float* W3 = (const float*)d_in[5];
  const float* b3 = (const float*)d_in[6];
  const int* starts = (const int*)d_in[7];
  float* out = (float*)d_out;
  char* ws = (char*)d_ws;

  const size_t A_BYTES   = (size_t)M_DIM * K_DIM * 2;          //   805,306,368
  const size_t W1T_BYTES = (size_t)NP * K_DIM * 2;             //    50,331,648
  const size_t H1P_BYTES = 3ull * M_DIM * NP * 4;              //   201,326,592
  const size_t W2T_BYTES = 40 * NP * 4;                        //       163,840
  const size_t B1P_BYTES = NP * 4;                             //         4,096
  const size_t LG_BYTES  = M_DIM * 4;                          //        65,536

  unsigned short* a    = (unsigned short*)ws;
  unsigned short* w1t  = (unsigned short*)(ws + A_BYTES);
  char* h1c            = ws + A_BYTES + W1T_BYTES;
  float* h1p           = (float*)h1c;
  float* w2t           = (float*)(ws + A_BYTES + W1T_BYTES + H1P_BYTES);
  float* b1p           = (float*)(ws + A_BYTES + W1T_BYTES + H1P_BYTES + W2T_BYTES);
  float* logits        = (float*)(ws + A_BYTES + W1T_BYTES + H1P_BYTES + W2T_BYTES + B1P_BYTES);
  int* idx             = (int*)(ws + A_BYTES + W1T_BYTES + H1P_BYTES + W2T_BYTES + B1P_BYTES + LG_BYTES);
  int* meta            = (int*)(ws + A_BYTES + W1T_BYTES + H1P_BYTES + W2T_BYTES + B1P_BYTES + LG_BYTES + 65536);
  // transient compaction scratch lives inside h1p (h1p is written only later)
  int* upos            = (int*)h1c;                 // 64 KiB
  int* counts          = (int*)(h1c + 65536);       // 128 B
  int* offs            = (int*)(h1c + 65536 + 128); // 128 B

  hipFuncSetAttribute((const void*)gemm1_8ph_kernel,
                      hipFuncAttributeMaxDynamicSharedMemorySize, 131072);

  compact1_kernel<<<32, 512, 0, stream>>>(starts, upos, counts);
  compact2_kernel<<<1, 256, 0, stream>>>(counts, offs, meta, idx);
  compact3_kernel<<<32, 512, 0, stream>>>(starts, upos, offs, idx);
  conv_a_kernel<<<2048, 256, 0, stream>>>(hs, idx, meta, a);
  prep_w1t_kernel<<<dim3(16, 384), 256, 0, stream>>>(W1, w1t);
  prep_small_kernel<<<164, 256, 0, stream>>>(W2, b1, w2t, b1p);
  gemm1_8ph_kernel<<<768, 512, 131072, stream>>>(a, w1t, meta, h1p);
  layer23_kernel<<<4096, 256, 0, stream>>>(h1p, w2t, b1p, b2, W3, b3, idx, meta, logits);
  gather_kernel<<<64, 256, 0, stream>>>(starts, logits, out);
}

// Round 13
// 1111.056 us; speedup vs baseline: 1.1173x; 1.1173x over previous
//
#include <hip/hip_runtime.h>

typedef __attribute__((ext_vector_type(8))) short bf16x8;
typedef __attribute__((ext_vector_type(4))) float f32x4;

#define L_DIM 24
#define B_DIM 32
#define S_DIM 512
#define H_DIM 1024
#define M_DIM 16384      // B*S
#define K_DIM 24576      // L*H
#define N_REAL 900
#define NP 1024          // padded N
#define BM 192           // m-tile (0.75x blocks -> 55 panels -> 220 actives)

// round-to-nearest-even fp32 -> bf16
__device__ __forceinline__ short f2bf(float f) {
  unsigned u = __builtin_bit_cast(unsigned, f);
  u += 0x7FFFu + ((u >> 16) & 1u);
  return (short)(u >> 16);
}

// ---- C1: per-batch flags + local prefix of unique nonzero starts (sorted input)
__global__ __launch_bounds__(512)
void compact1_kernel(const int* __restrict__ starts, int* __restrict__ upos,
                     int* __restrict__ counts) {
  __shared__ int sc[512];
  const int b = blockIdx.x, t = threadIdx.x;
  const int v = starts[b * 512 + t];
  const int prev = (t > 0) ? starts[b * 512 + t - 1] : -1;
  const int flag = (v != 0 && v != prev) ? 1 : 0;
  sc[t] = flag;
  __syncthreads();
#pragma unroll
  for (int off = 1; off < 512; off <<= 1) {
    const int x = (t >= off) ? sc[t - off] : 0;
    __syncthreads();
    sc[t] += x;
    __syncthreads();
  }
  upos[b * 512 + t] = flag ? (sc[t] - 1) : -1;
  if (t == 511) counts[b] = sc[511];
}

// ---- C2: scan counts -> offsets, Mc, Mc_pad (192-mult); pad idx tail with row 0
__global__ __launch_bounds__(256)
void compact2_kernel(const int* __restrict__ counts, int* __restrict__ offs,
                     int* __restrict__ meta, int* __restrict__ idx) {
  __shared__ int s0, s1;
  if (threadIdx.x == 0) {
    int acc = 0;
    for (int b = 0; b < 32; ++b) { offs[b] = acc; acc += counts[b]; }
    const int pad = ((acc + BM - 1) / BM) * BM;
    meta[0] = acc;                        // Mc
    meta[1] = pad;                        // Mc_pad (BM multiple)
    s0 = acc; s1 = pad;
  }
  __syncthreads();
  for (int j = s0 + threadIdx.x; j < s1; j += 256) idx[j] = 0;  // pad -> row 0
}

// ---- C3: scatter compact indices: idx[off_b + pos] = b*512 + value
__global__ __launch_bounds__(512)
void compact3_kernel(const int* __restrict__ starts, const int* __restrict__ upos,
                     const int* __restrict__ offs, int* __restrict__ idx) {
  const int b = blockIdx.x, t = threadIdx.x;
  const int p = upos[b * 512 + t];
  if (p >= 0) idx[offs[b] + p] = b * 512 + starts[b * 512 + t];
}

// ---- P0: compacted A: row j <- hs row idx[j], fp32->bf16, pre-swizzled by j&7:
// element (j,k) at k' = (k & ~63) + (((k>>3 & 7) ^ (j & 7)) * 8) + (k & 7)
__global__ __launch_bounds__(256)
void conv_a_kernel(const float* __restrict__ hs, const int* __restrict__ idx,
                   const int* __restrict__ meta, unsigned short* __restrict__ a) {
  const int mcp = meta[1];
  for (int j = blockIdx.x; j < mcp; j += gridDim.x) {
    const int m = idx[j];
    const int b = m >> 9, s = m & 511;
    const int j7 = j & 7;
    unsigned short* dstRow = a + (size_t)j * K_DIM;
#pragma unroll
    for (int i = 0; i < 12; ++i) {
      const int g = threadIdx.x + i * 256;        // granule (8 elems)
      const int l = g >> 7;
      const int h = (g & 127) * 8;
      const float* src = hs + (((size_t)l * B_DIM + b) * S_DIM + s) * H_DIM + h;
      float4 f0 = *(const float4*)src;
      float4 f1 = *(const float4*)(src + 4);
      bf16x8 p;
      p[0] = f2bf(f0.x); p[1] = f2bf(f0.y); p[2] = f2bf(f0.z); p[3] = f2bf(f0.w);
      p[4] = f2bf(f1.x); p[5] = f2bf(f1.y); p[6] = f2bf(f1.z); p[7] = f2bf(f1.w);
      const int slot = (g & 7) ^ j7;
      *(bf16x8*)(dstRow + (g & ~7) * 8 + slot * 8) = p;
    }
  }
}

// ---- P1: W1 [K][900] -> W1T bf16 [1024][K], zero-padded rows, swizzled (by n&7)
__global__ __launch_bounds__(256)
void prep_w1t_kernel(const float* __restrict__ w1, unsigned short* __restrict__ w1t) {
  __shared__ unsigned short t[64][72];
  const int n0 = blockIdx.x * 64;
  const int k0 = blockIdx.y * 64;
  const int tid = threadIdx.x;
  {
    const int nl = tid & 63;
    const int n = n0 + nl;
#pragma unroll
    for (int p = 0; p < 16; ++p) {
      const int kl = p * 4 + (tid >> 6);
      float v = (n < N_REAL) ? w1[(size_t)(k0 + kl) * N_REAL + n] : 0.f;
      t[nl][kl] = (unsigned short)f2bf(v);
    }
  }
  __syncthreads();
  {
    const int kl = tid & 63;
#pragma unroll
    for (int p = 0; p < 16; ++p) {
      const int nl2 = p * 4 + (tid >> 6);
      const int n = n0 + nl2;
      const int slot = ((kl >> 3) ^ (n & 7)) & 7;
      w1t[(size_t)n * K_DIM + k0 + slot * 8 + (kl & 7)] = t[nl2][kl];
    }
  }
}

// ---- P2: W2T fp32 [40][1024] (transposed, padded) + b1 padded [1024]
__global__ __launch_bounds__(256)
void prep_small_kernel(const float* __restrict__ w2, const float* __restrict__ b1,
                       float* __restrict__ w2t, float* __restrict__ b1p) {
  const int i = blockIdx.x * 256 + threadIdx.x;
  if (i < 40 * NP) {
    const int j = i >> 10, k = i & (NP - 1);
    w2t[i] = (k < N_REAL) ? w2[(size_t)k * 40 + j] : 0.f;
  }
  const int t2 = i - 40 * NP;
  if (t2 >= 0 && t2 < NP)
    b1p[t2] = (t2 < N_REAL) ? b1[t2] : 0.f;
}

// =====================================================================
// G1: h1 = relu(A @ W1T^T + b1). 192x256 tile, BK=64, 3-phase cadence.
// 55 panels x 4 n-blocks = 220 active blocks (86% CU fill, one round),
// full-K per block, panel's 4 consumers share one XCD (R11 mapping).
// Per tile: ph1 {read Aa+Ba, stage A(t+1) full: 3 ld/thr}, ph2 {read Bb,
// stage Bb(t+1): 2}, ph3 {read Ab, stage Ba(t+2): 2, 24 MFMA, vmcnt(2)}.
// Queue at each ph3-end: [Ba(t+1)2, A(t+1)3, Bb(t+1)2, Ba(t+2)2];
// vmcnt(2) lands exactly tile t+1's needs. LDS 112 KiB.
// =====================================================================
#define SBAR() do { __builtin_amdgcn_sched_barrier(0); __builtin_amdgcn_s_barrier(); __builtin_amdgcn_sched_barrier(0); } while (0)
#define WAIT_LGKM0() do { asm volatile("s_waitcnt lgkmcnt(0)" ::: "memory"); __builtin_amdgcn_sched_barrier(0); } while (0)
#define VMWAIT(N) do { asm volatile("s_waitcnt vmcnt(" #N ")" ::: "memory"); __builtin_amdgcn_sched_barrier(0); } while (0)

// stage full 192-row A tile (24 KiB): 3 x global_load_lds per thread
#define STAGE_A(DSTREG, TK) do {                                                       \
  _Pragma("unroll")                                                                    \
  for (int _i = 0; _i < 3; ++_i) {                                                     \
    const int _ch = wid * 3 + _i;                                                      \
    const int _row = _ch * 8 + (lane >> 3);                                            \
    __builtin_amdgcn_global_load_lds(                                                  \
      (const __attribute__((address_space(1))) void*)(a +                              \
          (size_t)(m0 + _row) * K_DIM + (TK) * 64 + (lane & 7) * 8),                   \
      (__attribute__((address_space(3))) void*)((DSTREG) + _ch * 1024),                \
      16, 0, 0);                                                                       \
  }                                                                                    \
} while (0)

// stage one 128-row half of B tile (16 KiB): 2 x global_load_lds per thread
#define STAGE_B(DSTREG, HALF, TK) do {                                                 \
  _Pragma("unroll")                                                                    \
  for (int _i = 0; _i < 2; ++_i) {                                                     \
    const int _ch = wid * 2 + _i;                                                      \
    const int _row = (HALF) * 128 + _ch * 8 + (lane >> 3);                             \
    __builtin_amdgcn_global_load_lds(                                                  \
      (const __attribute__((address_space(1))) void*)(w1t +                            \
          (size_t)(n0 + _row) * K_DIM + (TK) * 64 + (lane & 7) * 8),                   \
      (__attribute__((address_space(3))) void*)((DSTREG) + (HALF) * 16384 + _ch * 1024), \
      16, 0, 0);                                                                       \
  }                                                                                    \
} while (0)

// A fragments: half h = MIBASE/3; rows h*96 + wr*48 + {0,16,32} + r15, both kk
#define LDA3(AV, MIBASE, ABUF) do {                                                    \
  _Pragma("unroll")                                                                    \
  for (int _mi = 0; _mi < 3; ++_mi) {                                                  \
    _Pragma("unroll")                                                                  \
    for (int _kk = 0; _kk < 2; ++_kk) {                                                \
      const int _r = ((MIBASE) / 3) * 96 + wr * 48 + _mi * 16 + r15;                   \
      AV[_mi][_kk] = *(const bf16x8*)((ABUF) + _r * 128 + (((_kk)*4 + hi4) ^ (_r & 7)) * 16); \
    }                                                                                  \
  }                                                                                    \
} while (0)

// B fragments: half = NIBASE>>1; rows half*128 + wc*32 + {0,16} + r15, both kk
#define LDB2(BV, NIBASE, BBUF) do {                                                    \
  _Pragma("unroll")                                                                    \
  for (int _ni = 0; _ni < 2; ++_ni) {                                                  \
    _Pragma("unroll")                                                                  \
    for (int _kk = 0; _kk < 2; ++_kk) {                                                \
      const int _r = ((NIBASE) >> 1) * 128 + wc * 32 + _ni * 16 + r15;                 \
      BV[_ni][_kk] = *(const bf16x8*)((BBUF) + _r * 128 + (((_kk)*4 + hi4) ^ (_r & 7)) * 16); \
    }                                                                                  \
  }                                                                                    \
} while (0)

#define MFMA_Q(AV, BV, MIBASE, NIBASE) do {                                            \
  _Pragma("unroll")                                                                    \
  for (int _mi = 0; _mi < 3; ++_mi)                                                    \
    _Pragma("unroll")                                                                  \
    for (int _ni = 0; _ni < 2; ++_ni)                                                  \
      _Pragma("unroll")                                                                \
      for (int _kk = 0; _kk < 2; ++_kk)                                                \
        acc[(MIBASE) + _mi][(NIBASE) + _ni] = __builtin_amdgcn_mfma_f32_16x16x32_bf16( \
            AV[_mi][_kk], BV[_ni][_kk], acc[(MIBASE) + _mi][(NIBASE) + _ni], 0, 0, 0); \
} while (0)

// one K-tile = 3 phases. S1: stage A(t+1) full into ABN; S2: Bb(t+1) into
// BBN; S3: Ba(t+2) into BB (current; half a last read at ph1).
#define TILE_BODY(T, AB, BB, ABN, BBN, S1, S2, S3, WAITSTMT) do {                      \
  /* ---- phase 1: Aa x Ba ---- */                                                     \
  LDA3(av, 0, (AB));                                                                   \
  LDB2(bv0, 0, (BB));                                                                  \
  if (S1) STAGE_A((ABN), (T) + 1);                                                     \
  SBAR();                                                                              \
  WAIT_LGKM0();                                                                        \
  __builtin_amdgcn_s_setprio(1);                                                       \
  MFMA_Q(av, bv0, 0, 0);                                                               \
  __builtin_amdgcn_s_setprio(0);                                                       \
  SBAR();                                                                              \
  /* ---- phase 2: Aa x Bb ---- */                                                     \
  LDB2(bv1, 2, (BB));                                                                  \
  if (S2) STAGE_B((BBN), 1, (T) + 1);                                                  \
  SBAR();                                                                              \
  WAIT_LGKM0();                                                                        \
  __builtin_amdgcn_s_setprio(1);                                                       \
  MFMA_Q(av, bv1, 0, 2);                                                               \
  __builtin_amdgcn_s_setprio(0);                                                       \
  SBAR();                                                                              \
  /* ---- phase 3: Ab x (Bb, Ba) ---- */                                               \
  LDA3(av, 3, (AB));                                                                   \
  if (S3) STAGE_B((BB), 0, (T) + 2);                                                   \
  SBAR();                                                                              \
  WAIT_LGKM0();                                                                        \
  __builtin_amdgcn_s_setprio(1);                                                       \
  MFMA_Q(av, bv1, 3, 2);                                                               \
  MFMA_Q(av, bv0, 3, 0);                                                               \
  __builtin_amdgcn_s_setprio(0);                                                       \
  WAITSTMT;                                                                            \
  SBAR();                                                                              \
} while (0)

__global__ __launch_bounds__(512, 2)
void gemm1_192_kernel(const unsigned short* __restrict__ a,
                      const unsigned short* __restrict__ w1t,
                      const float* __restrict__ b1p,
                      const int* __restrict__ meta,
                      float* __restrict__ h1) {
  const int n_panels = meta[1] / BM;

  // XCD mapping: panel mb's 4 n-blocks share XCD c = mb&7; actives are the
  // contiguous prefix hw < 4*n_panels-ish (inactives exit instantly).
  const int hw = blockIdx.x;
  const int c = hw & 7;
  const int r = hw >> 3;              // 0..43
  const int mb = (r >> 2) * 8 + c;
  if (mb >= n_panels) return;
  const int nb = r & 3;
  const int m0 = mb * BM;
  const int n0 = nb * 256;

  extern __shared__ char L[];   // 112 KiB: A0(24K)|A1(24K)|B0(32K)|B1(32K)
  char* const Ab0 = L;
  char* const Ab1 = L + 24576;
  char* const Bb0 = L + 49152;
  char* const Bb1 = L + 49152 + 32768;

  const int tid = threadIdx.x;
  const int lane = tid & 63;
  const int wid = tid >> 6;          // 0..7
  const int wr = wid >> 2;           // 0..1 (48-row band within each 96-half)
  const int wc = wid & 3;            // 0..3 (32-col band within each 128-half)
  const int r15 = lane & 15;
  const int hi4 = lane >> 4;         // 0..3

  f32x4 acc[6][4] = {};
  bf16x8 av[3][2], bv0[2][2], bv1[2][2];

  // prologue, steady queue order: [Ba(0)2, A(0)3, Bb(0)2, Ba(1)2]
  STAGE_B(Bb0, 0, 0);
  STAGE_A(Ab0, 0);
  STAGE_B(Bb0, 1, 0);
  STAGE_B(Bb1, 0, 1);
  VMWAIT(2);      // land Ba(0), A(0), Bb(0); keep Ba(1) in flight
  SBAR();

  for (int kt = 0; kt < 191; ++kt) {
    const int t = 2 * kt;
    TILE_BODY(t,     Ab0, Bb0, Ab1, Bb1, 1, 1, 1, VMWAIT(2));
    TILE_BODY(t + 1, Ab1, Bb1, Ab0, Bb0, 1, 1, 1, VMWAIT(2));
  }
  // tail: 382 stages A(383)+Bb(383), full drain; 383 computes only
  TILE_BODY(382, Ab0, Bb0, Ab1, Bb1, 1, 1, 0, VMWAIT(0));
  TILE_BODY(383, Ab1, Bb1, Ab0, Bb0, 0, 0, 0, (void)0);

  // epilogue: relu(acc + b1); C/D: col = lane&15, row = (lane>>4)*4 + rr
#pragma unroll
  for (int mi = 0; mi < 6; ++mi) {
#pragma unroll
    for (int ni = 0; ni < 4; ++ni) {
      const int n = n0 + (ni >> 1) * 128 + wc * 32 + (ni & 1) * 16 + r15;
      const float bias = b1p[n];
#pragma unroll
      for (int rr = 0; rr < 4; ++rr) {
        const int m = m0 + (mi / 3) * 96 + wr * 48 + (mi % 3) * 16 + hi4 * 4 + rr;
        const float v = acc[mi][ni][rr] + bias;
        h1[(size_t)m * NP + n] = v > 0.f ? v : 0.f;
      }
    }
  }
}

// ---- K2: logits = sigmoid(relu(h1 @ W2 + b2) @ W3 + b3), one wave per
//          COMPACT row j; writes logits at the original position idx[j].
__global__ __launch_bounds__(256)
void layer23_kernel(const float* __restrict__ h1, const float* __restrict__ w2t,
                    const float* __restrict__ b2, const float* __restrict__ w3,
                    const float* __restrict__ b3, const int* __restrict__ idx,
                    const int* __restrict__ meta, float* __restrict__ logits) {
  const int j = (blockIdx.x * 256 + threadIdx.x) >> 6;
  if (j >= meta[0]) return;
  const int lane = threadIdx.x & 63;
  const float* hrow = h1 + (size_t)j * NP;
  float acc = 0.f;
  if (lane < 40) {
    const float* wrow = w2t + lane * NP;
    for (int k = 0; k < NP; k += 8) {
      float4 h0 = *(const float4*)(hrow + k);
      float4 h4 = *(const float4*)(hrow + k + 4);
      float4 w0 = *(const float4*)(wrow + k);
      float4 w4 = *(const float4*)(wrow + k + 4);
      acc += h0.x * w0.x + h0.y * w0.y + h0.z * w0.z + h0.w * w0.w;
      acc += h4.x * w4.x + h4.y * w4.y + h4.z * w4.z + h4.w * w4.w;
    }
    acc += b2[lane];
    acc = acc > 0.f ? acc : 0.f;
    acc *= w3[lane];
  }
#pragma unroll
  for (int off = 32; off > 0; off >>= 1)
    acc += __shfl_down(acc, off);
  if (lane == 0)
    logits[idx[j]] = 1.f / (1.f + expf(-(acc + b3[0])));
}

// ---- K3: ragged gather
__global__ __launch_bounds__(256)
void gather_kernel(const int* __restrict__ starts, const float* __restrict__ logits,
                   float* __restrict__ out) {
  const int i = blockIdx.x * 256 + threadIdx.x;
  if (i >= M_DIM) return;
  const int st = starts[i];
  int idx = st;
  if (idx < 0) idx = 0;
  if (idx > S_DIM - 1) idx = S_DIM - 1;
  out[i] = (st != 0) ? logits[((i >> 9) << 9) + idx] : 0.f;
}

extern "C" void kernel_launch(void* const* d_in, const int* in_sizes, int n_in,
                              void* d_out, int out_size, void* d_ws, size_t ws_size,
                              hipStream_t stream) {
  const float* hs = (const float*)d_in[0];
  const float* W1 = (const float*)d_in[1];
  const float* b1 = (const float*)d_in[2];
  const float* W2 = (const float*)d_in[3];
  const float* b2 = (const float*)d_in[4];
  const float* W3 = (const float*)d_in[5];
  const float* b3 = (const float*)d_in[6];
  const int* starts = (const int*)d_in[7];
  float* out = (float*)d_out;
  char* ws = (char*)d_ws;

  const size_t A_BYTES   = (size_t)(M_DIM + 256) * K_DIM * 2;  // slack for 192-pad
  const size_t W1T_BYTES = (size_t)NP * K_DIM * 2;             //    50,331,648
  const size_t H1_BYTES  = (size_t)(M_DIM + 256) * NP * 4;
  const size_t W2T_BYTES = 40 * NP * 4;
  const size_t B1P_BYTES = NP * 4;
  const size_t LG_BYTES  = M_DIM * 4;

  unsigned short* a    = (unsigned short*)ws;
  unsigned short* w1t  = (unsigned short*)(ws + A_BYTES);
  char* h1c            = ws + A_BYTES + W1T_BYTES;
  float* h1            = (float*)h1c;
  float* w2t           = (float*)(ws + A_BYTES + W1T_BYTES + H1_BYTES);
  float* b1p           = (float*)(ws + A_BYTES + W1T_BYTES + H1_BYTES + W2T_BYTES);
  float* logits        = (float*)(ws + A_BYTES + W1T_BYTES + H1_BYTES + W2T_BYTES + B1P_BYTES);
  int* idx             = (int*)(ws + A_BYTES + W1T_BYTES + H1_BYTES + W2T_BYTES + B1P_BYTES + LG_BYTES);
  int* meta            = (int*)(ws + A_BYTES + W1T_BYTES + H1_BYTES + W2T_BYTES + B1P_BYTES + LG_BYTES + 66560);
  // transient compaction scratch lives inside h1 (h1 is written only later)
  int* upos            = (int*)h1c;                 // 64 KiB
  int* counts          = (int*)(h1c + 65536);       // 128 B
  int* offs            = (int*)(h1c + 65536 + 128); // 128 B

  hipFuncSetAttribute((const void*)gemm1_192_kernel,
                      hipFuncAttributeMaxDynamicSharedMemorySize, 114688);

  compact1_kernel<<<32, 512, 0, stream>>>(starts, upos, counts);
  compact2_kernel<<<1, 256, 0, stream>>>(counts, offs, meta, idx);
  compact3_kernel<<<32, 512, 0, stream>>>(starts, upos, offs, idx);
  conv_a_kernel<<<2048, 256, 0, stream>>>(hs, idx, meta, a);
  prep_w1t_kernel<<<dim3(16, 384), 256, 0, stream>>>(W1, w1t);
  prep_small_kernel<<<164, 256, 0, stream>>>(W2, b1, w2t, b1p);
  gemm1_192_kernel<<<352, 512, 114688, stream>>>(a, w1t, b1p, meta, h1);
  layer23_kernel<<<4096, 256, 0, stream>>>(h1, w2t, b2, W3, b3, idx, meta, logits);
  gather_kernel<<<64, 256, 0, stream>>>(starts, logits, out);
}

// Round 14
// 1083.172 us; speedup vs baseline: 1.1461x; 1.0257x over previous
//
#include <hip/hip_runtime.h>

typedef __attribute__((ext_vector_type(8))) short bf16x8;
typedef __attribute__((ext_vector_type(4))) float f32x4;

#define L_DIM 24
#define B_DIM 32
#define S_DIM 512
#define H_DIM 1024
#define M_DIM 16384      // B*S
#define K_DIM 24576      // L*H
#define N_REAL 900
#define NP 1024          // padded N
#define BM 192           // m-tile (0.75x blocks -> ~55 panels -> ~220 actives)

#define W1T_TILES 6144   // 16 x 384 tiles of 64x64
#define SMALL_CHUNKS 164

// round-to-nearest-even fp32 -> bf16
__device__ __forceinline__ short f2bf(float f) {
  unsigned u = __builtin_bit_cast(unsigned, f);
  u += 0x7FFFu + ((u >> 16) & 1u);
  return (short)(u >> 16);
}

// ---- C1: per-batch flags + local prefix of unique nonzero starts (sorted input)
__global__ __launch_bounds__(512)
void compact1_kernel(const int* __restrict__ starts, int* __restrict__ upos,
                     int* __restrict__ counts) {
  __shared__ int sc[512];
  const int b = blockIdx.x, t = threadIdx.x;
  const int v = starts[b * 512 + t];
  const int prev = (t > 0) ? starts[b * 512 + t - 1] : -1;
  const int flag = (v != 0 && v != prev) ? 1 : 0;
  sc[t] = flag;
  __syncthreads();
#pragma unroll
  for (int off = 1; off < 512; off <<= 1) {
    const int x = (t >= off) ? sc[t - off] : 0;
    __syncthreads();
    sc[t] += x;
    __syncthreads();
  }
  upos[b * 512 + t] = flag ? (sc[t] - 1) : -1;
  if (t == 511) counts[b] = sc[511];
}

// ---- C2: scan counts -> offsets, Mc, Mc_pad (192-mult); pad idx tail with row 0
__global__ __launch_bounds__(256)
void compact2_kernel(const int* __restrict__ counts, int* __restrict__ offs,
                     int* __restrict__ meta, int* __restrict__ idx) {
  __shared__ int s0, s1;
  if (threadIdx.x == 0) {
    int acc = 0;
    for (int b = 0; b < 32; ++b) { offs[b] = acc; acc += counts[b]; }
    const int pad = ((acc + BM - 1) / BM) * BM;
    meta[0] = acc;                        // Mc
    meta[1] = pad;                        // Mc_pad (BM multiple)
    s0 = acc; s1 = pad;
  }
  __syncthreads();
  for (int j = s0 + threadIdx.x; j < s1; j += 256) idx[j] = 0;  // pad -> row 0
}

// ---- C3: scatter compact indices: idx[off_b + pos] = b*512 + value
__global__ __launch_bounds__(512)
void compact3_kernel(const int* __restrict__ starts, const int* __restrict__ upos,
                     const int* __restrict__ offs, int* __restrict__ idx) {
  const int b = blockIdx.x, t = threadIdx.x;
  const int p = upos[b * 512 + t];
  if (p >= 0) idx[offs[b] + p] = b * 512 + starts[b * 512 + t];
}

// =====================================================================
// P-fused: one kernel, three memory-bound work types co-resident so HBM
// stays saturated (they previously ran serially):
//   item < 6144              : one 64x64 W1->W1T transpose tile
//   item < 6144+Mc_pad       : one compacted-A row convert (fp32->bf16)
//   item < 6144+Mc_pad+164   : one prep_small chunk (W2T + b1p)
// Each block-iteration takes ONE branch (uniform) -> inner syncthreads ok.
// =====================================================================
__global__ __launch_bounds__(256)
void prep_fused_kernel(const float* __restrict__ hs, const int* __restrict__ idx,
                       const int* __restrict__ meta,
                       const float* __restrict__ w1, const float* __restrict__ w2,
                       const float* __restrict__ b1,
                       unsigned short* __restrict__ a,
                       unsigned short* __restrict__ w1t,
                       float* __restrict__ w2t, float* __restrict__ b1p) {
  __shared__ unsigned short t[64][72];
  const int mcp = meta[1];
  const int total = W1T_TILES + mcp + SMALL_CHUNKS;
  const int tid = threadIdx.x;

  for (int item = blockIdx.x; item < total; item += gridDim.x) {
    if (item < W1T_TILES) {
      // ---- W1T tile: 64 n-cols x 64 k-rows, transpose via LDS, swizzle by n&7
      const int n0 = (item & 15) * 64;
      const int k0 = (item >> 4) * 64;
      {
        const int nl = tid & 63;
        const int n = n0 + nl;
#pragma unroll
        for (int p = 0; p < 16; ++p) {
          const int kl = p * 4 + (tid >> 6);
          float v = (n < N_REAL) ? w1[(size_t)(k0 + kl) * N_REAL + n] : 0.f;
          t[nl][kl] = (unsigned short)f2bf(v);
        }
      }
      __syncthreads();
      {
        const int kl = tid & 63;
#pragma unroll
        for (int p = 0; p < 16; ++p) {
          const int nl2 = p * 4 + (tid >> 6);
          const int n = n0 + nl2;
          const int slot = ((kl >> 3) ^ (n & 7)) & 7;
          w1t[(size_t)n * K_DIM + k0 + slot * 8 + (kl & 7)] = t[nl2][kl];
        }
      }
      __syncthreads();   // protect t[][] before next iteration reuses it
    } else if (item < W1T_TILES + mcp) {
      // ---- compacted A row j <- hs row idx[j], pre-swizzled by j&7:
      // element (j,k) at k' = (k&~63) + (((k>>3&7)^(j&7))*8) + (k&7)
      const int j = item - W1T_TILES;
      const int m = idx[j];
      const int b = m >> 9, s = m & 511;
      const int j7 = j & 7;
      unsigned short* dstRow = a + (size_t)j * K_DIM;
#pragma unroll
      for (int i = 0; i < 12; ++i) {
        const int g = tid + i * 256;        // granule (8 elems)
        const int l = g >> 7;
        const int h = (g & 127) * 8;
        const float* src = hs + (((size_t)l * B_DIM + b) * S_DIM + s) * H_DIM + h;
        float4 f0 = *(const float4*)src;
        float4 f1 = *(const float4*)(src + 4);
        bf16x8 p;
        p[0] = f2bf(f0.x); p[1] = f2bf(f0.y); p[2] = f2bf(f0.z); p[3] = f2bf(f0.w);
        p[4] = f2bf(f1.x); p[5] = f2bf(f1.y); p[6] = f2bf(f1.z); p[7] = f2bf(f1.w);
        const int slot = (g & 7) ^ j7;
        *(bf16x8*)(dstRow + (g & ~7) * 8 + slot * 8) = p;
      }
    } else {
      // ---- prep_small chunk: W2T fp32 [40][1024] + b1 padded [1024]
      const int i = (item - W1T_TILES - mcp) * 256 + tid;
      if (i < 40 * NP) {
        const int jj = i >> 10, k = i & (NP - 1);
        w2t[i] = (k < N_REAL) ? w2[(size_t)k * 40 + jj] : 0.f;
      }
      const int t2 = i - 40 * NP;
      if (t2 >= 0 && t2 < NP)
        b1p[t2] = (t2 < N_REAL) ? b1[t2] : 0.f;
    }
  }
}

// =====================================================================
// G1: h1 = relu(A @ W1T^T + b1). 192x256 tile, BK=64, 3-phase cadence.
// (R13-verified, byte-identical.) ~55 panels x 4 n-blocks = ~220 active
// blocks (86% CU fill, one round), full-K per block, panel-per-XCD.
// =====================================================================
#define SBAR() do { __builtin_amdgcn_sched_barrier(0); __builtin_amdgcn_s_barrier(); __builtin_amdgcn_sched_barrier(0); } while (0)
#define WAIT_LGKM0() do { asm volatile("s_waitcnt lgkmcnt(0)" ::: "memory"); __builtin_amdgcn_sched_barrier(0); } while (0)
#define VMWAIT(N) do { asm volatile("s_waitcnt vmcnt(" #N ")" ::: "memory"); __builtin_amdgcn_sched_barrier(0); } while (0)

// stage full 192-row A tile (24 KiB): 3 x global_load_lds per thread
#define STAGE_A(DSTREG, TK) do {                                                       \
  _Pragma("unroll")                                                                    \
  for (int _i = 0; _i < 3; ++_i) {                                                     \
    const int _ch = wid * 3 + _i;                                                      \
    const int _row = _ch * 8 + (lane >> 3);                                            \
    __builtin_amdgcn_global_load_lds(                                                  \
      (const __attribute__((address_space(1))) void*)(a +                              \
          (size_t)(m0 + _row) * K_DIM + (TK) * 64 + (lane & 7) * 8),                   \
      (__attribute__((address_space(3))) void*)((DSTREG) + _ch * 1024),                \
      16, 0, 0);                                                                       \
  }                                                                                    \
} while (0)

// stage one 128-row half of B tile (16 KiB): 2 x global_load_lds per thread
#define STAGE_B(DSTREG, HALF, TK) do {                                                 \
  _Pragma("unroll")                                                                    \
  for (int _i = 0; _i < 2; ++_i) {                                                     \
    const int _ch = wid * 2 + _i;                                                      \
    const int _row = (HALF) * 128 + _ch * 8 + (lane >> 3);                             \
    __builtin_amdgcn_global_load_lds(                                                  \
      (const __attribute__((address_space(1))) void*)(w1t +                            \
          (size_t)(n0 + _row) * K_DIM + (TK) * 64 + (lane & 7) * 8),                   \
      (__attribute__((address_space(3))) void*)((DSTREG) + (HALF) * 16384 + _ch * 1024), \
      16, 0, 0);                                                                       \
  }                                                                                    \
} while (0)

// A fragments: half h = MIBASE/3; rows h*96 + wr*48 + {0,16,32} + r15, both kk
#define LDA3(AV, MIBASE, ABUF) do {                                                    \
  _Pragma("unroll")                                                                    \
  for (int _mi = 0; _mi < 3; ++_mi) {                                                  \
    _Pragma("unroll")                                                                  \
    for (int _kk = 0; _kk < 2; ++_kk) {                                                \
      const int _r = ((MIBASE) / 3) * 96 + wr * 48 + _mi * 16 + r15;                   \
      AV[_mi][_kk] = *(const bf16x8*)((ABUF) + _r * 128 + (((_kk)*4 + hi4) ^ (_r & 7)) * 16); \
    }                                                                                  \
  }                                                                                    \
} while (0)

// B fragments: half = NIBASE>>1; rows half*128 + wc*32 + {0,16} + r15, both kk
#define LDB2(BV, NIBASE, BBUF) do {                                                    \
  _Pragma("unroll")                                                                    \
  for (int _ni = 0; _ni < 2; ++_ni) {                                                  \
    _Pragma("unroll")                                                                  \
    for (int _kk = 0; _kk < 2; ++_kk) {                                                \
      const int _r = ((NIBASE) >> 1) * 128 + wc * 32 + _ni * 16 + r15;                 \
      BV[_ni][_kk] = *(const bf16x8*)((BBUF) + _r * 128 + (((_kk)*4 + hi4) ^ (_r & 7)) * 16); \
    }                                                                                  \
  }                                                                                    \
} while (0)

#define MFMA_Q(AV, BV, MIBASE, NIBASE) do {                                            \
  _Pragma("unroll")                                                                    \
  for (int _mi = 0; _mi < 3; ++_mi)                                                    \
    _Pragma("unroll")                                                                  \
    for (int _ni = 0; _ni < 2; ++_ni)                                                  \
      _Pragma("unroll")                                                                \
      for (int _kk = 0; _kk < 2; ++_kk)                                                \
        acc[(MIBASE) + _mi][(NIBASE) + _ni] = __builtin_amdgcn_mfma_f32_16x16x32_bf16( \
            AV[_mi][_kk], BV[_ni][_kk], acc[(MIBASE) + _mi][(NIBASE) + _ni], 0, 0, 0); \
} while (0)

// one K-tile = 3 phases. S1: stage A(t+1) full into ABN; S2: Bb(t+1) into
// BBN; S3: Ba(t+2) into BB (current; half a last read at ph1).
#define TILE_BODY(T, AB, BB, ABN, BBN, S1, S2, S3, WAITSTMT) do {                      \
  /* ---- phase 1: Aa x Ba ---- */                                                     \
  LDA3(av, 0, (AB));                                                                   \
  LDB2(bv0, 0, (BB));                                                                  \
  if (S1) STAGE_A((ABN), (T) + 1);                                                     \
  SBAR();                                                                              \
  WAIT_LGKM0();                                                                        \
  __builtin_amdgcn_s_setprio(1);                                                       \
  MFMA_Q(av, bv0, 0, 0);                                                               \
  __builtin_amdgcn_s_setprio(0);                                                       \
  SBAR();                                                                              \
  /* ---- phase 2: Aa x Bb ---- */                                                     \
  LDB2(bv1, 2, (BB));                                                                  \
  if (S2) STAGE_B((BBN), 1, (T) + 1);                                                  \
  SBAR();                                                                              \
  WAIT_LGKM0();                                                                        \
  __builtin_amdgcn_s_setprio(1);                                                       \
  MFMA_Q(av, bv1, 0, 2);                                                               \
  __builtin_amdgcn_s_setprio(0);                                                       \
  SBAR();                                                                              \
  /* ---- phase 3: Ab x (Bb, Ba) ---- */                                               \
  LDA3(av, 3, (AB));                                                                   \
  if (S3) STAGE_B((BB), 0, (T) + 2);                                                   \
  SBAR();                                                                              \
  WAIT_LGKM0();                                                                        \
  __builtin_amdgcn_s_setprio(1);                                                       \
  MFMA_Q(av, bv1, 3, 2);                                                               \
  MFMA_Q(av, bv0, 3, 0);                                                               \
  __builtin_amdgcn_s_setprio(0);                                                       \
  WAITSTMT;                                                                            \
  SBAR();                                                                              \
} while (0)

__global__ __launch_bounds__(512, 2)
void gemm1_192_kernel(const unsigned short* __restrict__ a,
                      const unsigned short* __restrict__ w1t,
                      const float* __restrict__ b1p,
                      const int* __restrict__ meta,
                      float* __restrict__ h1) {
  const int n_panels = meta[1] / BM;

  // XCD mapping: panel mb's 4 n-blocks share XCD c = mb&7
  const int hw = blockIdx.x;
  const int c = hw & 7;
  const int r = hw >> 3;              // 0..43
  const int mb = (r >> 2) * 8 + c;
  if (mb >= n_panels) return;
  const int nb = r & 3;
  const int m0 = mb * BM;
  const int n0 = nb * 256;

  extern __shared__ char L[];   // 112 KiB: A0(24K)|A1(24K)|B0(32K)|B1(32K)
  char* const Ab0 = L;
  char* const Ab1 = L + 24576;
  char* const Bb0 = L + 49152;
  char* const Bb1 = L + 49152 + 32768;

  const int tid = threadIdx.x;
  const int lane = tid & 63;
  const int wid = tid >> 6;          // 0..7
  const int wr = wid >> 2;           // 0..1 (48-row band within each 96-half)
  const int wc = wid & 3;            // 0..3 (32-col band within each 128-half)
  const int r15 = lane & 15;
  const int hi4 = lane >> 4;         // 0..3

  f32x4 acc[6][4] = {};
  bf16x8 av[3][2], bv0[2][2], bv1[2][2];

  // prologue, steady queue order: [Ba(0)2, A(0)3, Bb(0)2, Ba(1)2]
  STAGE_B(Bb0, 0, 0);
  STAGE_A(Ab0, 0);
  STAGE_B(Bb0, 1, 0);
  STAGE_B(Bb1, 0, 1);
  VMWAIT(2);      // land Ba(0), A(0), Bb(0); keep Ba(1) in flight
  SBAR();

  for (int kt = 0; kt < 191; ++kt) {
    const int t = 2 * kt;
    TILE_BODY(t,     Ab0, Bb0, Ab1, Bb1, 1, 1, 1, VMWAIT(2));
    TILE_BODY(t + 1, Ab1, Bb1, Ab0, Bb0, 1, 1, 1, VMWAIT(2));
  }
  // tail: 382 stages A(383)+Bb(383), full drain; 383 computes only
  TILE_BODY(382, Ab0, Bb0, Ab1, Bb1, 1, 1, 0, VMWAIT(0));
  TILE_BODY(383, Ab1, Bb1, Ab0, Bb0, 0, 0, 0, (void)0);

  // epilogue: relu(acc + b1); C/D: col = lane&15, row = (lane>>4)*4 + rr
#pragma unroll
  for (int mi = 0; mi < 6; ++mi) {
#pragma unroll
    for (int ni = 0; ni < 4; ++ni) {
      const int n = n0 + (ni >> 1) * 128 + wc * 32 + (ni & 1) * 16 + r15;
      const float bias = b1p[n];
#pragma unroll
      for (int rr = 0; rr < 4; ++rr) {
        const int m = m0 + (mi / 3) * 96 + wr * 48 + (mi % 3) * 16 + hi4 * 4 + rr;
        const float v = acc[mi][ni][rr] + bias;
        h1[(size_t)m * NP + n] = v > 0.f ? v : 0.f;
      }
    }
  }
}

// ---- K2: logits = sigmoid(relu(h1 @ W2 + b2) @ W3 + b3), one wave per
//          COMPACT row j; writes logits at the original position idx[j].
__global__ __launch_bounds__(256)
void layer23_kernel(const float* __restrict__ h1, const float* __restrict__ w2t,
                    const float* __restrict__ b2, const float* __restrict__ w3,
                    const float* __restrict__ b3, const int* __restrict__ idx,
                    const int* __restrict__ meta, float* __restrict__ logits) {
  const int j = (blockIdx.x * 256 + threadIdx.x) >> 6;
  if (j >= meta[0]) return;
  const int lane = threadIdx.x & 63;
  const float* hrow = h1 + (size_t)j * NP;
  float acc = 0.f;
  if (lane < 40) {
    const float* wrow = w2t + lane * NP;
    for (int k = 0; k < NP; k += 8) {
      float4 h0 = *(const float4*)(hrow + k);
      float4 h4 = *(const float4*)(hrow + k + 4);
      float4 w0 = *(const float4*)(wrow + k);
      float4 w4 = *(const float4*)(wrow + k + 4);
      acc += h0.x * w0.x + h0.y * w0.y + h0.z * w0.z + h0.w * w0.w;
      acc += h4.x * w4.x + h4.y * w4.y + h4.z * w4.z + h4.w * w4.w;
    }
    acc += b2[lane];
    acc = acc > 0.f ? acc : 0.f;
    acc *= w3[lane];
  }
#pragma unroll
  for (int off = 32; off > 0; off >>= 1)
    acc += __shfl_down(acc, off);
  if (lane == 0)
    logits[idx[j]] = 1.f / (1.f + expf(-(acc + b3[0])));
}

// ---- K3: ragged gather
__global__ __launch_bounds__(256)
void gather_kernel(const int* __restrict__ starts, const float* __restrict__ logits,
                   float* __restrict__ out) {
  const int i = blockIdx.x * 256 + threadIdx.x;
  if (i >= M_DIM) return;
  const int st = starts[i];
  int idx = st;
  if (idx < 0) idx = 0;
  if (idx > S_DIM - 1) idx = S_DIM - 1;
  out[i] = (st != 0) ? logits[((i >> 9) << 9) + idx] : 0.f;
}

extern "C" void kernel_launch(void* const* d_in, const int* in_sizes, int n_in,
                              void* d_out, int out_size, void* d_ws, size_t ws_size,
                              hipStream_t stream) {
  const float* hs = (const float*)d_in[0];
  const float* W1 = (const float*)d_in[1];
  const float* b1 = (const float*)d_in[2];
  const float* W2 = (const float*)d_in[3];
  const float* b2 = (const float*)d_in[4];
  const float* W3 = (const float*)d_in[5];
  const float* b3 = (const float*)d_in[6];
  const int* starts = (const int*)d_in[7];
  float* out = (float*)d_out;
  char* ws = (char*)d_ws;

  const size_t A_BYTES   = (size_t)(M_DIM + 256) * K_DIM * 2;  // slack for 192-pad
  const size_t W1T_BYTES = (size_t)NP * K_DIM * 2;             //    50,331,648
  const size_t H1_BYTES  = (size_t)(M_DIM + 256) * NP * 4;
  const size_t W2T_BYTES = 40 * NP * 4;
  const size_t B1P_BYTES = NP * 4;
  const size_t LG_BYTES  = M_DIM * 4;

  unsigned short* a    = (unsigned short*)ws;
  unsigned short* w1t  = (unsigned short*)(ws + A_BYTES);
  char* h1c            = ws + A_BYTES + W1T_BYTES;
  float* h1            = (float*)h1c;
  float* w2t           = (float*)(ws + A_BYTES + W1T_BYTES + H1_BYTES);
  float* b1p           = (float*)(ws + A_BYTES + W1T_BYTES + H1_BYTES + W2T_BYTES);
  float* logits        = (float*)(ws + A_BYTES + W1T_BYTES + H1_BYTES + W2T_BYTES + B1P_BYTES);
  int* idx             = (int*)(ws + A_BYTES + W1T_BYTES + H1_BYTES + W2T_BYTES + B1P_BYTES + LG_BYTES);
  int* meta            = (int*)(ws + A_BYTES + W1T_BYTES + H1_BYTES + W2T_BYTES + B1P_BYTES + LG_BYTES + 66560);
  // transient compaction scratch lives inside h1 (h1 is written only later)
  int* upos            = (int*)h1c;                 // 64 KiB
  int* counts          = (int*)(h1c + 65536);       // 128 B
  int* offs            = (int*)(h1c + 65536 + 128); // 128 B

  hipFuncSetAttribute((const void*)gemm1_192_kernel,
                      hipFuncAttributeMaxDynamicSharedMemorySize, 114688);

  compact1_kernel<<<32, 512, 0, stream>>>(starts, upos, counts);
  compact2_kernel<<<1, 256, 0, stream>>>(counts, offs, meta, idx);
  compact3_kernel<<<32, 512, 0, stream>>>(starts, upos, offs, idx);
  prep_fused_kernel<<<4096, 256, 0, stream>>>(hs, idx, meta, W1, W2, b1,
                                              a, w1t, w2t, b1p);
  gemm1_192_kernel<<<352, 512, 114688, stream>>>(a, w1t, b1p, meta, h1);
  layer23_kernel<<<4096, 256, 0, stream>>>(h1, w2t, b2, W3, b3, idx, meta, logits);
  gather_kernel<<<64, 256, 0, stream>>>(starts, logits, out);
}